// Round 7
// baseline (330.692 us; speedup 1.0000x reference)
//
#include <hip/hip_runtime.h>
#include <hip/hip_bf16.h>

typedef unsigned short ushort_t;
typedef __bf16 bf16x8 __attribute__((ext_vector_type(8)));
typedef float floatx4 __attribute__((ext_vector_type(4)));

#define MFMA(a, b, c) __builtin_amdgcn_mfma_f32_16x16x32_bf16(a, b, c, 0, 0, 0)

// HARDWARE bf16 convert: plain fptrunc lowers to v_cvt_pk_bf16_f32 on gfx950
// (RNE, same rounding as software __float2bfloat16, ~5x fewer VALU ops).
__device__ __forceinline__ ushort_t f2b(float f) {
    union { ushort_t u; __bf16 h; } cvt; cvt.h = (__bf16)f; return cvt.u;
}

// async global->LDS, 16 B/lane. Dest = wave-uniform base + lane*16.
__device__ __forceinline__ void async_copy16(const ushort_t* g, ushort_t* l) {
    __builtin_amdgcn_global_load_lds(
        (const __attribute__((address_space(1))) void*)g,
        (__attribute__((address_space(3))) void*)l, 16, 0, 0);
}

// ---------------------------------------------------------------------------
// Merged preprocessing: one launch, three block-ranges.
// ---------------------------------------------------------------------------
__global__ void prep(const float* __restrict__ xin, ushort_t* __restrict__ xb,
                     const float* __restrict__ Wqkv, ushort_t* __restrict__ WqkvT,
                     const float* __restrict__ Wo, ushort_t* __restrict__ WoT) {
    __shared__ float tile[32][33];
    int bb = blockIdx.x;
    if (bb < 4096) {
        int i = bb * 256 + threadIdx.x;
        const float4* xf = (const float4*)xin;
        float4 a = xf[i * 2], b = xf[i * 2 + 1];
        union { ushort_t s[8]; uint4 v; } p;
        p.s[0] = f2b(a.x); p.s[1] = f2b(a.y); p.s[2] = f2b(a.z); p.s[3] = f2b(a.w);
        p.s[4] = f2b(b.x); p.s[5] = f2b(b.y); p.s[6] = f2b(b.z); p.s[7] = f2b(b.w);
        ((uint4*)xb)[i] = p.v;
    } else if (bb < 7168) {
        int b2 = bb - 4096;
        int p0 = (b2 % 96) * 32, k0 = (b2 / 96) * 32;
        int which = p0 >> 10, rem = p0 & 1023;
        int n0 = (rem >> 6) * 192 + which * 64 + (rem & 63);
        int tx = threadIdx.x & 31, ty = threadIdx.x >> 5;
#pragma unroll
        for (int i = 0; i < 4; ++i)
            tile[ty + i * 8][tx] = Wqkv[(size_t)(k0 + ty + i * 8) * 3072 + n0 + tx];
        __syncthreads();
#pragma unroll
        for (int i = 0; i < 4; ++i)
            WqkvT[(size_t)(p0 + ty + i * 8) * 1024 + k0 + tx] = f2b(tile[tx][ty + i * 8]);
    } else {
        int b3 = bb - 7168;
        int n0 = (b3 & 31) * 32, k0 = (b3 >> 5) * 32;
        int tx = threadIdx.x & 31, ty = threadIdx.x >> 5;
#pragma unroll
        for (int i = 0; i < 4; ++i)
            tile[ty + i * 8][tx] = Wo[(size_t)(k0 + ty + i * 8) * 1024 + n0 + tx];
        __syncthreads();
#pragma unroll
        for (int i = 0; i < 4; ++i)
            WoT[(size_t)(n0 + ty + i * 8) * 1024 + k0 + tx] = f2b(tile[tx][ty + i * 8]);
    }
}

// swizzled index into the 128x128 transpose buffer
__device__ __forceinline__ int tswz(int n, int m) {
    return n * 128 + (((m >> 3) ^ (n & 15)) << 3) + (m & 7);
}

// ---------------------------------------------------------------------------
// GEMM1: qkv = x @ Wqkv_perm + b.  Q PRE-SCALED by 0.125*log2(e).
// NATURAL block order (XCD-chunked swizzle measured WORSE: FETCH 44->181 MB).
// ---------------------------------------------------------------------------
__global__ __launch_bounds__(256, 4) void gemm_qkv(
    const ushort_t* __restrict__ A,
    const ushort_t* __restrict__ Bt,
    const float* __restrict__ bias,
    ushort_t* __restrict__ Qb, ushort_t* __restrict__ Kb, ushort_t* __restrict__ Vtb) {
    const int K = 1024;
    __shared__ __align__(16) ushort_t SH[16384];
    ushort_t* Alds = SH;
    ushort_t* Blds = SH + 8192;
    int tid = threadIdx.x;
    int wave = tid >> 6, lane = tid & 63;
    int quad = lane >> 4, l16 = lane & 15;
    int wm = (wave >> 1) * 64, wn = (wave & 1) * 64;
    int m0 = blockIdx.x * 128, n0 = blockIdx.y * 128;

    floatx4 acc[4][4] = {};

    int srow[4], scol[4];
#pragma unroll
    for (int p = 0; p < 4; ++p) {
        int slot = (wave * 4 + p) * 64 + lane;
        int row = slot >> 3;
        srow[p] = row;
        scol[p] = ((slot & 7) ^ (row & 7)) * 8;
    }

    for (int kt = 0; kt < 16; ++kt) {
        int k0 = kt * 64;
        __syncthreads();
#pragma unroll
        for (int p = 0; p < 4; ++p) {
            int t = wave * 4 + p;
            async_copy16(&A[(m0 + srow[p]) * K + k0 + scol[p]], &Alds[t * 512]);
            async_copy16(&Bt[(n0 + srow[p]) * K + k0 + scol[p]], &Blds[t * 512]);
        }
        __syncthreads();
#pragma unroll
        for (int ki = 0; ki < 2; ++ki) {
            bf16x8 af[4], bfv[4];
            int sc = ((ki * 4 + quad) ^ (l16 & 7)) * 8;
#pragma unroll
            for (int i = 0; i < 4; ++i) {
                __builtin_memcpy(&af[i],  &Alds[(wm + i * 16 + l16) * 64 + sc], 16);
                __builtin_memcpy(&bfv[i], &Blds[(wn + i * 16 + l16) * 64 + sc], 16);
            }
#pragma unroll
            for (int i = 0; i < 4; ++i)
#pragma unroll
                for (int j = 0; j < 4; ++j)
                    acc[i][j] = MFMA(af[i], bfv[j], acc[i][j]);
        }
    }

    int which = n0 >> 10;              // 0=Q, 1=K, 2=V
    int b = m0 >> 10;

    if (which < 2) {
        ushort_t* dst = which ? Kb : Qb;
        float sc = which ? 1.0f : 0.18033688f;   // Q pre-scale: 0.125*log2(e)
#pragma unroll
        for (int j = 0; j < 4; ++j) {
            int C = n0 + wn + j * 16 + l16;
            int c = C & 1023;
            int h = c >> 6, d = c & 63;
            float bv = bias[((C >> 6) & 15) * 192 + which * 64 + (C & 63)];
            size_t hb = (size_t)(b * 16 + h) * 65536 + d;
#pragma unroll
            for (int i = 0; i < 4; ++i)
#pragma unroll
                for (int g = 0; g < 4; ++g) {
                    int n_tok = (m0 & 1023) + wm + i * 16 + quad * 4 + g;
                    dst[hb + (size_t)n_tok * 64] = f2b((acc[i][j][g] + bv) * sc);
                }
        }
    } else {
        __syncthreads();
#pragma unroll
        for (int j = 0; j < 4; ++j) {
            int C = n0 + wn + j * 16 + l16;
            int nl2 = wn + j * 16 + l16;
            float bv = bias[((C >> 6) & 15) * 192 + 128 + (C & 63)];
#pragma unroll
            for (int i = 0; i < 4; ++i)
#pragma unroll
                for (int g = 0; g < 4; ++g) {
                    int ml = wm + i * 16 + quad * 4 + g;
                    SH[tswz(nl2, ml)] = f2b(acc[i][j][g] + bv);
                }
        }
        __syncthreads();
        int r = tid >> 1, half = tid & 1;
        int vcol = (n0 - 2048) + r;
        int h = vcol >> 6, d = vcol & 63;
        size_t base = ((size_t)(b * 16 + h) * 64 + d) * 1024 + (m0 & 1023) + half * 64;
#pragma unroll
        for (int i8 = 0; i8 < 8; ++i8) {
            int chunk = half * 8 + i8;
            uint4 v;
            __builtin_memcpy(&v, &SH[r * 128 + ((chunk ^ (r & 15)) << 3)], 16);
            __builtin_memcpy(&Vtb[base + i8 * 8], &v, 16);
        }
    }
}

// ---------------------------------------------------------------------------
// Flash attention v9: double-buffered K/V in 32 KB total.  P OVERLAYS the
// current K-half (dead once kf is in regs; barrier-B protects cross-wave).
// Raw barriers with counted waits:
//   barrier-A: s_waitcnt vmcnt(0) + s_barrier   (staged tile ready)
//   ... kf ds_reads; ISSUE next-tile global_load_lds (stays in flight!) ...
//   barrier-B: s_waitcnt lgkmcnt(0) + s_barrier (kf safe; K-half now free)
// Stage latency hides under the whole S+softmax+PV phase (T14).
// P layout [64][64] with per-4-chunk rotation col'=(col+4*l16)&63:
// 2*l16 mod 32 is BIJECTIVE per 16-lane quad-phase -> conflict-free
// (the r5 XOR swizzle collapsed l16/l16+8 -> 2.1M conflicts; reverted).
// ---------------------------------------------------------------------------
__global__ __launch_bounds__(256, 4) void attn(
    const ushort_t* __restrict__ Qb, const ushort_t* __restrict__ Kb,
    const ushort_t* __restrict__ Vtb, ushort_t* __restrict__ heads) {
    __shared__ __align__(16) ushort_t KV[2][2][4096];   // [buf][K|V][64x64]
    int tid = threadIdx.x;
    int wave = tid >> 6, lane = tid & 63;
    int quad = lane >> 4, l16 = lane & 15;

    // XCD-aware remap: blockIdx.x IS the XCD; q-tiles iterate fastest.
    int slot = blockIdx.y + 16 * blockIdx.z;
    int bh = blockIdx.x + 8 * (slot >> 3);
    int qx = slot & 7;
    int b = bh >> 4, h = bh & 15;
    const ushort_t* Qh = Qb + (size_t)bh * 65536;
    const ushort_t* Kh = Kb + (size_t)bh * 65536;
    const ushort_t* Vh = Vtb + (size_t)bh * 65536;

    bf16x8 qa[2][2];                   // [mi][ki], B-fragment role
#pragma unroll
    for (int mi = 0; mi < 2; ++mi) {
        int qrow = qx * 128 + wave * 32 + mi * 16 + l16;
        __builtin_memcpy(&qa[mi][0], &Qh[qrow * 64 + quad * 8], 16);
        __builtin_memcpy(&qa[mi][1], &Qh[qrow * 64 + 32 + quad * 8], 16);
    }

    floatx4 oacc[2][4] = {};
    floatx4 oext[2] = {};

    bf16x8 onesfrag;
    {
        ushort_t v = (l16 == 0) ? (ushort_t)0x3F80 : (ushort_t)0;
        ushort_t tmp[8] = {v, v, v, v, v, v, v, v};
        __builtin_memcpy(&onesfrag, tmp, 16);
    }

    int srow[2], scol[2];
#pragma unroll
    for (int p = 0; p < 2; ++p) {
        int slot2 = (wave * 2 + p) * 64 + lane;
        int row = slot2 >> 3;
        srow[p] = row;
        scol[p] = ((slot2 & 7) ^ (row & 7)) * 8;
    }

    // prologue: stage tile 0 into buffer 0
#pragma unroll
    for (int p = 0; p < 2; ++p) {
        int t = wave * 2 + p;
        async_copy16(&Kh[srow[p] * 64 + scol[p]], &KV[0][0][t * 512]);
        async_copy16(&Vh[srow[p] * 1024 + scol[p]], &KV[0][1][t * 512]);
    }

    int prot = l16 * 4;                // P chunk rotation (bijective per quad)
    int prow64 = (wave * 16 + l16) * 64;

    for (int kt = 0; kt < 16; ++kt) {
        int cur = kt & 1;

        // ---- barrier-A: staged buffer ready; prev tile fully consumed
        asm volatile("s_waitcnt vmcnt(0)" ::: "memory");
        __builtin_amdgcn_sched_barrier(0);
        __builtin_amdgcn_s_barrier();
        __builtin_amdgcn_sched_barrier(0);

        // kf from K-half of current buffer
        bf16x8 kf[4][2];
#pragma unroll
        for (int n = 0; n < 4; ++n)
#pragma unroll
            for (int ki = 0; ki < 2; ++ki) {
                int sc = ((ki * 4 + quad) ^ (l16 & 7)) * 8;
                __builtin_memcpy(&kf[n][ki], &KV[cur][0][(n * 16 + l16) * 64 + sc], 16);
            }

        // issue next-tile stage into the other buffer (stays in flight
        // across barrier-B; drained only at next barrier-A)
        if (kt < 15) {
            int nk0 = (kt + 1) * 64, nb = cur ^ 1;
#pragma unroll
            for (int p = 0; p < 2; ++p) {
                int t = wave * 2 + p;
                async_copy16(&Kh[(nk0 + srow[p]) * 64 + scol[p]], &KV[nb][0][t * 512]);
                async_copy16(&Vh[srow[p] * 1024 + nk0 + scol[p]], &KV[nb][1][t * 512]);
            }
        }

        // ---- barrier-B: all waves' kf reads complete -> K-half reusable
        asm volatile("s_waitcnt lgkmcnt(0)" ::: "memory");
        __builtin_amdgcn_sched_barrier(0);
        __builtin_amdgcn_s_barrier();
        __builtin_amdgcn_sched_barrier(0);

        // vf from V-half (never overlaid)
        bf16x8 vf[4][2];
#pragma unroll
        for (int n = 0; n < 4; ++n)
#pragma unroll
            for (int ki = 0; ki < 2; ++ki) {
                int sc = ((ki * 4 + quad) ^ (l16 & 7)) * 8;
                __builtin_memcpy(&vf[n][ki], &KV[cur][1][(n * 16 + l16) * 64 + sc], 16);
            }

        ushort_t* Pl = &KV[cur][0][0];     // P overlay on dead K-half
#pragma unroll
        for (int mi = 0; mi < 2; ++mi) {
            // S = K Q^T; P = exp2(S) -> overlay (rotated chunks)
#pragma unroll
            for (int n = 0; n < 4; ++n) {
                floatx4 z = {0.f, 0.f, 0.f, 0.f};
#pragma unroll
                for (int ki = 0; ki < 2; ++ki)
                    z = MFMA(kf[n][ki], qa[mi][ki], z);
                union { ushort_t s[4]; double d8; } pk;
#pragma unroll
                for (int g = 0; g < 4; ++g)
                    pk.s[g] = f2b(__builtin_exp2f(z[g]));
                __builtin_memcpy(&Pl[prow64 + ((n * 16 + quad * 4 + prot) & 63)],
                                 &pk, 8);
            }
            // pa read-back (same-wave DS order; 2x b64 per ki — rotated
            // chunks may be non-adjacent)
            bf16x8 pa[2];
#pragma unroll
            for (int ki = 0; ki < 2; ++ki) {
                double lo, hi;
                __builtin_memcpy(&lo, &Pl[prow64 + ((ki * 32 + quad * 8 + prot) & 63)], 8);
                __builtin_memcpy(&hi, &Pl[prow64 + ((ki * 32 + quad * 8 + 4 + prot) & 63)], 8);
                double t2[2] = {lo, hi};
                __builtin_memcpy(&pa[ki], t2, 16);
            }
            __builtin_amdgcn_s_setprio(1);
#pragma unroll
            for (int n = 0; n < 4; ++n)
#pragma unroll
                for (int ki = 0; ki < 2; ++ki)
                    oacc[mi][n] = MFMA(pa[ki], vf[n][ki], oacc[mi][n]);
#pragma unroll
            for (int ki = 0; ki < 2; ++ki)
                oext[mi] = MFMA(pa[ki], onesfrag, oext[mi]);
            __builtin_amdgcn_s_setprio(0);
        }
    }

    // normalize + write heads (B, N, H*HD) bf16
#pragma unroll
    for (int mi = 0; mi < 2; ++mi)
#pragma unroll
        for (int g = 0; g < 4; ++g) {
            float l = __shfl(oext[mi][g], (lane & 48));
            float inv = 1.f / l;
            int n_tok = qx * 128 + wave * 32 + mi * 16 + quad * 4 + g;
#pragma unroll
            for (int n = 0; n < 4; ++n)
                heads[(size_t)(b * 1024 + n_tok) * 1024 + h * 64 + n * 16 + l16] =
                    f2b(oacc[mi][n][g] * inv);
        }
}

// ---------------------------------------------------------------------------
// GEMM2: out = heads(8192x1024) @ W_o + b_o  -> FP32 d_out.  Natural order.
// ---------------------------------------------------------------------------
__global__ __launch_bounds__(256, 4) void gemm_out(
    const ushort_t* __restrict__ A,
    const ushort_t* __restrict__ Bt,
    const float* __restrict__ bias,
    float* __restrict__ out) {
    const int K = 1024;
    __shared__ __align__(16) ushort_t Alds[128 * 64];
    __shared__ __align__(16) ushort_t Blds[128 * 64];
    int tid = threadIdx.x;
    int wave = tid >> 6, lane = tid & 63;
    int quad = lane >> 4, l16 = lane & 15;
    int wm = (wave >> 1) * 64, wn = (wave & 1) * 64;
    int m0 = blockIdx.x * 128, n0 = blockIdx.y * 128;

    floatx4 acc[4][4] = {};

    int srow[4], scol[4];
#pragma unroll
    for (int p = 0; p < 4; ++p) {
        int slot = (wave * 4 + p) * 64 + lane;
        int row = slot >> 3;
        srow[p] = row;
        scol[p] = ((slot & 7) ^ (row & 7)) * 8;
    }

    for (int kt = 0; kt < 16; ++kt) {
        int k0 = kt * 64;
        __syncthreads();
#pragma unroll
        for (int p = 0; p < 4; ++p) {
            int t = wave * 4 + p;
            async_copy16(&A[(m0 + srow[p]) * K + k0 + scol[p]], &Alds[t * 512]);
            async_copy16(&Bt[(n0 + srow[p]) * K + k0 + scol[p]], &Blds[t * 512]);
        }
        __syncthreads();
#pragma unroll
        for (int ki = 0; ki < 2; ++ki) {
            bf16x8 af[4], bfv[4];
            int sc = ((ki * 4 + quad) ^ (l16 & 7)) * 8;
#pragma unroll
            for (int i = 0; i < 4; ++i) {
                __builtin_memcpy(&af[i],  &Alds[(wm + i * 16 + l16) * 64 + sc], 16);
                __builtin_memcpy(&bfv[i], &Blds[(wn + i * 16 + l16) * 64 + sc], 16);
            }
#pragma unroll
            for (int i = 0; i < 4; ++i)
#pragma unroll
                for (int j = 0; j < 4; ++j)
                    acc[i][j] = MFMA(af[i], bfv[j], acc[i][j]);
        }
    }

#pragma unroll
    for (int j = 0; j < 4; ++j) {
        int C = n0 + wn + j * 16 + l16;
        float bv = bias[C];
#pragma unroll
        for (int i = 0; i < 4; ++i)
#pragma unroll
            for (int g = 0; g < 4; ++g) {
                int R = m0 + wm + i * 16 + quad * 4 + g;
                out[(size_t)R * 1024 + C] = acc[i][j][g] + bv;
            }
    }
}

// ---------------------------------------------------------------------------
extern "C" void kernel_launch(void* const* d_in, const int* in_sizes, int n_in,
                              void* d_out, int out_size, void* d_ws, size_t ws_size,
                              hipStream_t stream) {
    const float* x    = (const float*)d_in[0];
    const float* Wqkv = (const float*)d_in[1];
    const float* bqkv = (const float*)d_in[2];
    const float* Wo   = (const float*)d_in[3];
    const float* bo   = (const float*)d_in[4];

    char* ws = (char*)d_ws;
    const size_t MB = 1u << 20;
    ushort_t* xb    = (ushort_t*)(ws);
    ushort_t* Qb    = (ushort_t*)(ws + 16 * MB);
    ushort_t* Kb    = (ushort_t*)(ws + 32 * MB);
    ushort_t* Vtb   = (ushort_t*)(ws + 48 * MB);
    ushort_t* WqkvT = (ushort_t*)(ws + 64 * MB);
    ushort_t* WoT   = (ushort_t*)(ws + 70 * MB);
    ushort_t* heads = (ushort_t*)(ws);             // alias xb

    prep<<<8192, 256, 0, stream>>>(x, xb, Wqkv, WqkvT, Wo, WoT);
    gemm_qkv<<<dim3(64, 24), 256, 0, stream>>>(xb, WqkvT, bqkv, Qb, Kb, Vtb);
    attn<<<dim3(8, 16, 8), 256, 0, stream>>>(Qb, Kb, Vtb, heads);
    gemm_out<<<dim3(64, 8), 256, 0, stream>>>(heads, WoT, bo, (float*)d_out);
}

// Round 8
// 221.931 us; speedup vs baseline: 1.4901x; 1.4901x over previous
//
#include <hip/hip_runtime.h>
#include <hip/hip_bf16.h>

typedef unsigned short ushort_t;
typedef __bf16 bf16x8 __attribute__((ext_vector_type(8)));
typedef float floatx4 __attribute__((ext_vector_type(4)));

#define MFMA(a, b, c) __builtin_amdgcn_mfma_f32_16x16x32_bf16(a, b, c, 0, 0, 0)

// HARDWARE bf16 convert: plain fptrunc lowers to v_cvt_pk_bf16_f32 on gfx950
// (RNE, same rounding as software __float2bfloat16, ~5x fewer VALU ops).
__device__ __forceinline__ ushort_t f2b(float f) {
    union { ushort_t u; __bf16 h; } cvt; cvt.h = (__bf16)f; return cvt.u;
}

// async global->LDS, 16 B/lane. Dest = wave-uniform base + lane*16.
__device__ __forceinline__ void async_copy16(const ushort_t* g, ushort_t* l) {
    __builtin_amdgcn_global_load_lds(
        (const __attribute__((address_space(1))) void*)g,
        (__attribute__((address_space(3))) void*)l, 16, 0, 0);
}

// ---------------------------------------------------------------------------
// Merged preprocessing: one launch, three block-ranges.
// ---------------------------------------------------------------------------
__global__ void prep(const float* __restrict__ xin, ushort_t* __restrict__ xb,
                     const float* __restrict__ Wqkv, ushort_t* __restrict__ WqkvT,
                     const float* __restrict__ Wo, ushort_t* __restrict__ WoT) {
    __shared__ float tile[32][33];
    int bb = blockIdx.x;
    if (bb < 4096) {
        int i = bb * 256 + threadIdx.x;
        const float4* xf = (const float4*)xin;
        float4 a = xf[i * 2], b = xf[i * 2 + 1];
        union { ushort_t s[8]; uint4 v; } p;
        p.s[0] = f2b(a.x); p.s[1] = f2b(a.y); p.s[2] = f2b(a.z); p.s[3] = f2b(a.w);
        p.s[4] = f2b(b.x); p.s[5] = f2b(b.y); p.s[6] = f2b(b.z); p.s[7] = f2b(b.w);
        ((uint4*)xb)[i] = p.v;
    } else if (bb < 7168) {
        int b2 = bb - 4096;
        int p0 = (b2 % 96) * 32, k0 = (b2 / 96) * 32;
        int which = p0 >> 10, rem = p0 & 1023;
        int n0 = (rem >> 6) * 192 + which * 64 + (rem & 63);
        int tx = threadIdx.x & 31, ty = threadIdx.x >> 5;
#pragma unroll
        for (int i = 0; i < 4; ++i)
            tile[ty + i * 8][tx] = Wqkv[(size_t)(k0 + ty + i * 8) * 3072 + n0 + tx];
        __syncthreads();
#pragma unroll
        for (int i = 0; i < 4; ++i)
            WqkvT[(size_t)(p0 + ty + i * 8) * 1024 + k0 + tx] = f2b(tile[tx][ty + i * 8]);
    } else {
        int b3 = bb - 7168;
        int n0 = (b3 & 31) * 32, k0 = (b3 >> 5) * 32;
        int tx = threadIdx.x & 31, ty = threadIdx.x >> 5;
#pragma unroll
        for (int i = 0; i < 4; ++i)
            tile[ty + i * 8][tx] = Wo[(size_t)(k0 + ty + i * 8) * 1024 + n0 + tx];
        __syncthreads();
#pragma unroll
        for (int i = 0; i < 4; ++i)
            WoT[(size_t)(n0 + ty + i * 8) * 1024 + k0 + tx] = f2b(tile[tx][ty + i * 8]);
    }
}

// swizzled index into the 128x128 transpose buffer
__device__ __forceinline__ int tswz(int n, int m) {
    return n * 128 + (((m >> 3) ^ (n & 15)) << 3) + (m & 7);
}

// ---------------------------------------------------------------------------
// GEMM1: qkv = x @ Wqkv_perm + b.  Q PRE-SCALED by 0.125*log2(e).
// NATURAL block order (XCD-chunked swizzle measured WORSE: FETCH 44->181 MB).
// ---------------------------------------------------------------------------
__global__ __launch_bounds__(256, 4) void gemm_qkv(
    const ushort_t* __restrict__ A,
    const ushort_t* __restrict__ Bt,
    const float* __restrict__ bias,
    ushort_t* __restrict__ Qb, ushort_t* __restrict__ Kb, ushort_t* __restrict__ Vtb) {
    const int K = 1024;
    __shared__ __align__(16) ushort_t SH[16384];
    ushort_t* Alds = SH;
    ushort_t* Blds = SH + 8192;
    int tid = threadIdx.x;
    int wave = tid >> 6, lane = tid & 63;
    int quad = lane >> 4, l16 = lane & 15;
    int wm = (wave >> 1) * 64, wn = (wave & 1) * 64;
    int m0 = blockIdx.x * 128, n0 = blockIdx.y * 128;

    floatx4 acc[4][4] = {};

    int srow[4], scol[4];
#pragma unroll
    for (int p = 0; p < 4; ++p) {
        int slot = (wave * 4 + p) * 64 + lane;
        int row = slot >> 3;
        srow[p] = row;
        scol[p] = ((slot & 7) ^ (row & 7)) * 8;
    }

    for (int kt = 0; kt < 16; ++kt) {
        int k0 = kt * 64;
        __syncthreads();
#pragma unroll
        for (int p = 0; p < 4; ++p) {
            int t = wave * 4 + p;
            async_copy16(&A[(m0 + srow[p]) * K + k0 + scol[p]], &Alds[t * 512]);
            async_copy16(&Bt[(n0 + srow[p]) * K + k0 + scol[p]], &Blds[t * 512]);
        }
        __syncthreads();
#pragma unroll
        for (int ki = 0; ki < 2; ++ki) {
            bf16x8 af[4], bfv[4];
            int sc = ((ki * 4 + quad) ^ (l16 & 7)) * 8;
#pragma unroll
            for (int i = 0; i < 4; ++i) {
                __builtin_memcpy(&af[i],  &Alds[(wm + i * 16 + l16) * 64 + sc], 16);
                __builtin_memcpy(&bfv[i], &Blds[(wn + i * 16 + l16) * 64 + sc], 16);
            }
#pragma unroll
            for (int i = 0; i < 4; ++i)
#pragma unroll
                for (int j = 0; j < 4; ++j)
                    acc[i][j] = MFMA(af[i], bfv[j], acc[i][j]);
        }
    }

    int which = n0 >> 10;              // 0=Q, 1=K, 2=V
    int b = m0 >> 10;

    if (which < 2) {
        ushort_t* dst = which ? Kb : Qb;
        float sc = which ? 1.0f : 0.18033688f;   // Q pre-scale: 0.125*log2(e)
#pragma unroll
        for (int j = 0; j < 4; ++j) {
            int C = n0 + wn + j * 16 + l16;
            int c = C & 1023;
            int h = c >> 6, d = c & 63;
            float bv = bias[((C >> 6) & 15) * 192 + which * 64 + (C & 63)];
            size_t hb = (size_t)(b * 16 + h) * 65536 + d;
#pragma unroll
            for (int i = 0; i < 4; ++i)
#pragma unroll
                for (int g = 0; g < 4; ++g) {
                    int n_tok = (m0 & 1023) + wm + i * 16 + quad * 4 + g;
                    dst[hb + (size_t)n_tok * 64] = f2b((acc[i][j][g] + bv) * sc);
                }
        }
    } else {
        __syncthreads();
#pragma unroll
        for (int j = 0; j < 4; ++j) {
            int C = n0 + wn + j * 16 + l16;
            int nl2 = wn + j * 16 + l16;
            float bv = bias[((C >> 6) & 15) * 192 + 128 + (C & 63)];
#pragma unroll
            for (int i = 0; i < 4; ++i)
#pragma unroll
                for (int g = 0; g < 4; ++g) {
                    int ml = wm + i * 16 + quad * 4 + g;
                    SH[tswz(nl2, ml)] = f2b(acc[i][j][g] + bv);
                }
        }
        __syncthreads();
        int r = tid >> 1, half = tid & 1;
        int vcol = (n0 - 2048) + r;
        int h = vcol >> 6, d = vcol & 63;
        size_t base = ((size_t)(b * 16 + h) * 64 + d) * 1024 + (m0 & 1023) + half * 64;
#pragma unroll
        for (int i8 = 0; i8 < 8; ++i8) {
            int chunk = half * 8 + i8;
            uint4 v;
            __builtin_memcpy(&v, &SH[r * 128 + ((chunk ^ (r & 15)) << 3)], 16);
            __builtin_memcpy(&Vtb[base + i8 * 8], &v, 16);
        }
    }
}

// ---------------------------------------------------------------------------
// Flash attention v10 == the measured-best r4 structure (60.3 us) + hw f2b.
// One 128-row q-tile per block, SINGLE-buffered K/V, two __syncthreads per
// K-tile, separate Plds [128][76] (pad-76: 6*l16 mod 32 bijective -> 0
// conflicts, measured).  LDS 35840 B -> 4 blocks/CU.  XCD remap keeps each
// XCD's K/V at 4 MB = its L2.  Q pre-scaled -> P = exp2(S) directly.
// v9 POST-MORTEM (do not retry as-was): P-overlay on dead K-half with
// double lo/hi + t2[] staging sent the P round-trip to SCRATCH (FETCH/WRITE
// +280 MB each, occupancy 2%, attn 158 us).  Any in-register P plan must
// use explicit u32 packing, no local arrays, and asm-verified codegen.
// ---------------------------------------------------------------------------
__global__ __launch_bounds__(256, 4) void attn(
    const ushort_t* __restrict__ Qb, const ushort_t* __restrict__ Kb,
    const ushort_t* __restrict__ Vtb, ushort_t* __restrict__ heads) {
    __shared__ __align__(16) ushort_t Klds[4096];       // swizzled, row = key
    __shared__ __align__(16) ushort_t Vlds[4096];       // swizzled, row = d
    __shared__ __align__(16) ushort_t Plds[128 * 76];   // [q-row][key], pad 76
    int tid = threadIdx.x;
    int wave = tid >> 6, lane = tid & 63;
    int quad = lane >> 4, l16 = lane & 15;

    // XCD-aware remap: blockIdx.x IS the XCD; q-tiles iterate fastest.
    int slot = blockIdx.y + 16 * blockIdx.z;
    int bh = blockIdx.x + 8 * (slot >> 3);
    int qx = slot & 7;
    int b = bh >> 4, h = bh & 15;
    const ushort_t* Qh = Qb + (size_t)bh * 65536;
    const ushort_t* Kh = Kb + (size_t)bh * 65536;
    const ushort_t* Vh = Vtb + (size_t)bh * 65536;

    bf16x8 qa[2][2];                   // [mi][ki], B-fragment role
#pragma unroll
    for (int mi = 0; mi < 2; ++mi) {
        int qrow = qx * 128 + wave * 32 + mi * 16 + l16;
        __builtin_memcpy(&qa[mi][0], &Qh[qrow * 64 + quad * 8], 16);
        __builtin_memcpy(&qa[mi][1], &Qh[qrow * 64 + 32 + quad * 8], 16);
    }

    floatx4 oacc[2][4] = {};
    floatx4 oext[2] = {};

    bf16x8 onesfrag;
    {
        ushort_t v = (l16 == 0) ? (ushort_t)0x3F80 : (ushort_t)0;
        ushort_t tmp[8] = {v, v, v, v, v, v, v, v};
        __builtin_memcpy(&onesfrag, tmp, 16);
    }

    int srow[2], scol[2];
#pragma unroll
    for (int p = 0; p < 2; ++p) {
        int slot2 = (wave * 2 + p) * 64 + lane;
        int row = slot2 >> 3;
        srow[p] = row;
        scol[p] = ((slot2 & 7) ^ (row & 7)) * 8;
    }

    for (int kt = 0; kt < 16; ++kt) {
        int k0 = kt * 64;
        __syncthreads();   // all waves done reading prev tile
#pragma unroll
        for (int p = 0; p < 2; ++p) {
            int t = wave * 2 + p;
            async_copy16(&Kh[(k0 + srow[p]) * 64 + scol[p]], &Klds[t * 512]);
            async_copy16(&Vh[srow[p] * 1024 + k0 + scol[p]], &Vlds[t * 512]);
        }
        __syncthreads();   // staged data visible (vmcnt drained by compiler)

        // ---- St = K Q^T; P = exp2(St) -> Plds
        bf16x8 kf[4][2];
#pragma unroll
        for (int n = 0; n < 4; ++n)
#pragma unroll
            for (int ki = 0; ki < 2; ++ki) {
                int sc = ((ki * 4 + quad) ^ (l16 & 7)) * 8;
                __builtin_memcpy(&kf[n][ki], &Klds[(n * 16 + l16) * 64 + sc], 16);
            }
#pragma unroll
        for (int mi = 0; mi < 2; ++mi) {
            int prow = wave * 32 + mi * 16 + l16;
#pragma unroll
            for (int n = 0; n < 4; ++n) {
                floatx4 z = {0.f, 0.f, 0.f, 0.f};
#pragma unroll
                for (int ki = 0; ki < 2; ++ki)
                    z = MFMA(kf[n][ki], qa[mi][ki], z);
                union { ushort_t s[4]; double d8; } pk;
#pragma unroll
                for (int g = 0; g < 4; ++g)
                    pk.s[g] = f2b(__builtin_exp2f(z[g]));
                __builtin_memcpy(
                    &Plds[prow * 76 + n * 16 + quad * 4], &pk, 8);
            }
        }

        // ---- O += P V ; l += P ones  (P read back same-wave, no barrier)
        bf16x8 vf[4][2];
#pragma unroll
        for (int n = 0; n < 4; ++n)
#pragma unroll
            for (int ki = 0; ki < 2; ++ki) {
                int sc = ((ki * 4 + quad) ^ (l16 & 7)) * 8;
                __builtin_memcpy(&vf[n][ki], &Vlds[(n * 16 + l16) * 64 + sc], 16);
            }
#pragma unroll
        for (int mi = 0; mi < 2; ++mi) {
            bf16x8 pa[2];
            int prow = wave * 32 + mi * 16 + l16;
#pragma unroll
            for (int ki = 0; ki < 2; ++ki)
                __builtin_memcpy(&pa[ki], &Plds[prow * 76 + ki * 32 + quad * 8], 16);
            __builtin_amdgcn_s_setprio(1);
#pragma unroll
            for (int n = 0; n < 4; ++n)
#pragma unroll
                for (int ki = 0; ki < 2; ++ki)
                    oacc[mi][n] = MFMA(pa[ki], vf[n][ki], oacc[mi][n]);
#pragma unroll
            for (int ki = 0; ki < 2; ++ki)
                oext[mi] = MFMA(pa[ki], onesfrag, oext[mi]);
            __builtin_amdgcn_s_setprio(0);
        }
    }

    // normalize + write heads (B, N, H*HD) bf16
#pragma unroll
    for (int mi = 0; mi < 2; ++mi)
#pragma unroll
        for (int g = 0; g < 4; ++g) {
            float l = __shfl(oext[mi][g], (lane & 48));
            float inv = 1.f / l;
            int n_tok = qx * 128 + wave * 32 + mi * 16 + quad * 4 + g;
#pragma unroll
            for (int n = 0; n < 4; ++n)
                heads[(size_t)(b * 1024 + n_tok) * 1024 + h * 64 + n * 16 + l16] =
                    f2b(oacc[mi][n][g] * inv);
        }
}

// ---------------------------------------------------------------------------
// GEMM2: out = heads(8192x1024) @ W_o + b_o  -> FP32 d_out.  Natural order.
// ---------------------------------------------------------------------------
__global__ __launch_bounds__(256, 4) void gemm_out(
    const ushort_t* __restrict__ A,
    const ushort_t* __restrict__ Bt,
    const float* __restrict__ bias,
    float* __restrict__ out) {
    const int K = 1024;
    __shared__ __align__(16) ushort_t Alds[128 * 64];
    __shared__ __align__(16) ushort_t Blds[128 * 64];
    int tid = threadIdx.x;
    int wave = tid >> 6, lane = tid & 63;
    int quad = lane >> 4, l16 = lane & 15;
    int wm = (wave >> 1) * 64, wn = (wave & 1) * 64;
    int m0 = blockIdx.x * 128, n0 = blockIdx.y * 128;

    floatx4 acc[4][4] = {};

    int srow[4], scol[4];
#pragma unroll
    for (int p = 0; p < 4; ++p) {
        int slot = (wave * 4 + p) * 64 + lane;
        int row = slot >> 3;
        srow[p] = row;
        scol[p] = ((slot & 7) ^ (row & 7)) * 8;
    }

    for (int kt = 0; kt < 16; ++kt) {
        int k0 = kt * 64;
        __syncthreads();
#pragma unroll
        for (int p = 0; p < 4; ++p) {
            int t = wave * 4 + p;
            async_copy16(&A[(m0 + srow[p]) * K + k0 + scol[p]], &Alds[t * 512]);
            async_copy16(&Bt[(n0 + srow[p]) * K + k0 + scol[p]], &Blds[t * 512]);
        }
        __syncthreads();
#pragma unroll
        for (int ki = 0; ki < 2; ++ki) {
            bf16x8 af[4], bfv[4];
            int sc = ((ki * 4 + quad) ^ (l16 & 7)) * 8;
#pragma unroll
            for (int i = 0; i < 4; ++i) {
                __builtin_memcpy(&af[i],  &Alds[(wm + i * 16 + l16) * 64 + sc], 16);
                __builtin_memcpy(&bfv[i], &Blds[(wn + i * 16 + l16) * 64 + sc], 16);
            }
#pragma unroll
            for (int i = 0; i < 4; ++i)
#pragma unroll
                for (int j = 0; j < 4; ++j)
                    acc[i][j] = MFMA(af[i], bfv[j], acc[i][j]);
        }
    }

#pragma unroll
    for (int j = 0; j < 4; ++j) {
        int C = n0 + wn + j * 16 + l16;
        float bv = bias[C];
#pragma unroll
        for (int i = 0; i < 4; ++i)
#pragma unroll
            for (int g = 0; g < 4; ++g) {
                int R = m0 + wm + i * 16 + quad * 4 + g;
                out[(size_t)R * 1024 + C] = acc[i][j][g] + bv;
            }
    }
}

// ---------------------------------------------------------------------------
extern "C" void kernel_launch(void* const* d_in, const int* in_sizes, int n_in,
                              void* d_out, int out_size, void* d_ws, size_t ws_size,
                              hipStream_t stream) {
    const float* x    = (const float*)d_in[0];
    const float* Wqkv = (const float*)d_in[1];
    const float* bqkv = (const float*)d_in[2];
    const float* Wo   = (const float*)d_in[3];
    const float* bo   = (const float*)d_in[4];

    char* ws = (char*)d_ws;
    const size_t MB = 1u << 20;
    ushort_t* xb    = (ushort_t*)(ws);
    ushort_t* Qb    = (ushort_t*)(ws + 16 * MB);
    ushort_t* Kb    = (ushort_t*)(ws + 32 * MB);
    ushort_t* Vtb   = (ushort_t*)(ws + 48 * MB);
    ushort_t* WqkvT = (ushort_t*)(ws + 64 * MB);
    ushort_t* WoT   = (ushort_t*)(ws + 70 * MB);
    ushort_t* heads = (ushort_t*)(ws);             // alias xb

    prep<<<8192, 256, 0, stream>>>(x, xb, Wqkv, WqkvT, Wo, WoT);
    gemm_qkv<<<dim3(64, 24), 256, 0, stream>>>(xb, WqkvT, bqkv, Qb, Kb, Vtb);
    attn<<<dim3(8, 16, 8), 256, 0, stream>>>(Qb, Kb, Vtb, heads);
    gemm_out<<<dim3(64, 8), 256, 0, stream>>>(heads, WoT, bo, (float*)d_out);
}